// Round 8
// baseline (402.455 us; speedup 1.0000x reference)
//
#include <hip/hip_runtime.h>
#include <stdint.h>

#define DEV __device__ __forceinline__

typedef __attribute__((ext_vector_type(8))) short bf16x8;
typedef __attribute__((ext_vector_type(4))) float f32x4;
typedef __attribute__((ext_vector_type(8))) unsigned short u16x8;

DEV unsigned short f2bf(float f) {
  union { float f; unsigned int u; } v; v.f = f;
  unsigned int u = v.u;
  return (unsigned short)((u + 0x7FFFu + ((u >> 16) & 1u)) >> 16);
}
DEV float bf2f(unsigned short u) {
  union { unsigned int u; float f; } v; v.u = ((unsigned int)u) << 16;
  return v.f;
}
DEV f32x4 mfma16(bf16x8 a, bf16x8 b, f32x4 c) {
  return __builtin_amdgcn_mfma_f32_16x16x32_bf16(a, b, c, 0, 0, 0);
}
DEV void gl_lds16(const void* g, void* l) {
  __builtin_amdgcn_global_load_lds(
      (const __attribute__((address_space(1))) void*)g,
      (__attribute__((address_space(3))) void*)l, 16, 0, 0);
}

// ======== launch 1: cvt (blocks 0..16383) + GK (blocks 16384..16511) ========
__global__ __launch_bounds__(256) void k_misc1(const float* __restrict__ x,
                                               unsigned short* __restrict__ xbf,
                                               const float* __restrict__ Wk,
                                               const float* __restrict__ qg,
                                               float* __restrict__ GK) {
  int bid = blockIdx.x;
  if (bid < 16384) {
    int i = bid * 256 + threadIdx.x;
    const float4* p = (const float4*)x + (size_t)i * 2;
    float4 a = p[0], b = p[1];
    u16x8 o;
    o[0] = f2bf(a.x); o[1] = f2bf(a.y); o[2] = f2bf(a.z); o[3] = f2bf(a.w);
    o[4] = f2bf(b.x); o[5] = f2bf(b.y); o[6] = f2bf(b.z); o[7] = f2bf(b.w);
    ((u16x8*)xbf)[i] = o;
  } else {
    int idx = (bid - 16384) * 256 + threadIdx.x;  // 32768: GK[h][s][dd]
    int dd = idx & 63, hs = idx >> 6;
    float a = 0.f;
#pragma unroll 8
    for (int d = 0; d < 64; ++d) a += Wk[dd * 64 + d] * qg[(size_t)hs * 64 + d];
    GK[idx] = a;
  }
}

// ======== launch 2: Wcat (head-interleaved) + WoT + bias ========
// Wcat row h*128+s (s<64) = Wl^T[hs]; row h*128+64+dp = Wv^T fused.
__global__ __launch_bounds__(256) void k_misc2(const float* __restrict__ Wx,
                                               const float* __restrict__ Wv,
                                               const float* __restrict__ Wo,
                                               const float* __restrict__ bx,
                                               const float* __restrict__ bk,
                                               const float* __restrict__ bv,
                                               const float* __restrict__ qg,
                                               const float* __restrict__ GK,
                                               unsigned short* __restrict__ Wcat,
                                               unsigned short* __restrict__ WoT,
                                               float* __restrict__ bias) {
  int bid = blockIdx.x;
  if (bid < 1024) {  // Wl
    int idx = bid * 256 + threadIdx.x;
    int c = idx & 511, hs = idx >> 9;
    int h = hs >> 6, s = hs & 63;
    float a = 0.f;
#pragma unroll 8
    for (int dd = 0; dd < 64; ++dd) a += Wx[(size_t)c * 512 + h * 64 + dd] * GK[hs * 64 + dd];
    Wcat[(size_t)(h * 128 + s) * 512 + c] = f2bf(a);
  } else if (bid < 2048) {  // Wv fused
    int idx = (bid - 1024) * 256 + threadIdx.x;
    int c = idx & 511, o = idx >> 9;
    int h = o >> 6, dp = o & 63;
    float a = 0.f;
#pragma unroll 8
    for (int dd = 0; dd < 64; ++dd) a += Wx[(size_t)c * 512 + h * 64 + dd] * Wv[dd * 64 + dp];
    Wcat[(size_t)(h * 128 + 64 + dp) * 512 + c] = f2bf(a);
  } else if (bid < 3072) {  // WoT
    int idx = (bid - 2048) * 256 + threadIdx.x;
    int i = idx >> 9, o = idx & 511;
    WoT[(size_t)o * 512 + i] = f2bf(Wo[(size_t)i * 512 + o]);
  } else {  // bias (head-interleaved): o=h*128+j; j<64 -> L-bias; else V-bias
    int o = (bid - 3072) * 256 + threadIdx.x;
    if (o >= 1024) return;
    int h = o >> 7, j = o & 127;
    if (j < 64) {
      int hs = h * 64 + j;
      float a = 0.f;
      for (int dd = 0; dd < 64; ++dd) a += bx[h * 64 + dd] * GK[(size_t)hs * 64 + dd];
      for (int dp = 0; dp < 64; ++dp) a += bk[dp] * qg[(size_t)hs * 64 + dp];
      bias[o] = a;
    } else {
      int dp = j - 64;
      float a = bv[dp];
      for (int dd = 0; dd < 64; ++dd) a += bx[h * 64 + dd] * Wv[dd * 64 + dp];
      bias[o] = a;
    }
  }
}

// =================== 128x128 GEMM, 4 waves, swizzled LDS, 4 blocks/CU ===================
// MODE 1 (GEMM1): grid 1024; each block = 4 M-tiles x 1 head. Epilogue per tile:
//   E=exp(L-8) -> P2 + ET/VT LDS transpose -> z_part accumulated in regs across
//   the 4 tiles (zpart 16MB). MODE 0 (GEMM2): grid 2048, swapped-operand MFMA ->
//   lane owns a row, regs own 4 consecutive cols -> dwordx4 stores.
template <int MODE>
__global__ __launch_bounds__(256, 4) void k_mm(const unsigned short* __restrict__ A,
                                               const unsigned short* __restrict__ BTg,
                                               const float* __restrict__ bias,
                                               unsigned short* __restrict__ P2,
                                               float* __restrict__ zpart,
                                               float* __restrict__ dpart,
                                               float* __restrict__ outF) {
  __shared__ __align__(16) char lds[35328];  // staging 32KB; epilogue ET/VT/denp
  const int tid = threadIdx.x;
  const int w = tid >> 6, lane = tid & 63, l = lane & 15, g = lane >> 4;
  unsigned bid = blockIdx.x;
  int group = 0, h = 0, mtile = 0, ntile = 0;
  if (MODE == 1) {  // 1024 blocks: XCD gets 16 groups x 8 heads, heads adjacent
    unsigned nbid = (bid & 7) * 128 + (bid >> 3);
    group = nbid >> 3;
    h = nbid & 7;
    ntile = h;
  } else {  // 2048 blocks: XCD gets 64 mtiles x 4 ntiles, ntiles adjacent
    unsigned nbid = (bid & 7) * 256 + (bid >> 3);
    mtile = nbid >> 2;
    ntile = nbid & 3;
  }
  const int bn = ntile * 128;
  const int wm = (w >> 1) * 64, wn = (w & 1) * 64;
  char* As = lds;
  char* Bs = lds + 16384;
  unsigned short* ET = (unsigned short*)lds;            // [64 s][136]
  unsigned short* VT = (unsigned short*)(lds + 17408);  // [64 d][136]
  float* denp = (float*)(lds + 34816);                  // [2][64]
  const int sw = (l & 7) << 4;
  f32x4 za[4] = {};
  float dtot = 0.f;

  for (int mt = 0; mt < (MODE ? 4 : 1); ++mt) {
    const int bm = MODE ? (group * 4 + mt) * 128 : mtile * 128;
    const unsigned short* BT = (MODE == 0) ? BTg + ((size_t)(bm >> 14) << 18) : BTg;
    f32x4 acc[4][4] = {};
    for (int t = 0; t < 8; ++t) {
#pragma unroll
      for (int i = 0; i < 4; ++i) {  // stage 16KB each of A,B (pre-swizzled src)
        int off = i * 4096 + tid * 16;
        int row = off >> 7;
        int cb = (off & 127) ^ ((row & 7) << 4);
        gl_lds16(A + (size_t)(bm + row) * 512 + t * 64 + (cb >> 1), As + off);
        gl_lds16(BT + (size_t)(bn + row) * 512 + t * 64 + (cb >> 1), Bs + off);
      }
      __syncthreads();
#pragma unroll
      for (int ks = 0; ks < 2; ++ks) {
        int kb = (ks * 64 + g * 16) ^ sw;
        bf16x8 af[4], bf[4];
#pragma unroll
        for (int fm = 0; fm < 4; ++fm)
          af[fm] = *(const bf16x8*)(As + (wm + fm * 16 + l) * 128 + kb);
#pragma unroll
        for (int fn = 0; fn < 4; ++fn)
          bf[fn] = *(const bf16x8*)(Bs + (wn + fn * 16 + l) * 128 + kb);
#pragma unroll
        for (int fm = 0; fm < 4; ++fm)
#pragma unroll
          for (int fn = 0; fn < 4; ++fn)
            acc[fm][fn] = (MODE == 0) ? mfma16(bf[fn], af[fm], acc[fm][fn])
                                      : mfma16(af[fm], bf[fn], acc[fm][fn]);
      }
      __syncthreads();
    }

    if (MODE == 0) {
      // swapped layout: out-row = bm+wm+fm*16+l, out-cols = bn+wn+fn*16+g*4+{0..3}
#pragma unroll
      for (int fm = 0; fm < 4; ++fm) {
        int row = bm + wm + fm * 16 + l;
#pragma unroll
        for (int fn = 0; fn < 4; ++fn) {
          int col0 = bn + wn + fn * 16 + g * 4;
          f32x4 b4 = *(const f32x4*)&bias[col0];
          f32x4 o;
#pragma unroll
          for (int r = 0; r < 4; ++r) o[r] = acc[fm][fn][r] + b4[r];
          *(f32x4*)&outF[(size_t)row * 512 + col0] = o;
        }
      }
      return;
    }

    // ================= MODE 1 per-tile epilogue =================
    float bc[4];
#pragma unroll
    for (int fn = 0; fn < 4; ++fn) bc[fn] = bias[h * 128 + wn + fn * 16 + l];
    if (wn == 0) {  // E-waves (cols 0..63 = slots)
#pragma unroll
      for (int fm = 0; fm < 4; ++fm)
#pragma unroll
        for (int fn = 0; fn < 4; ++fn)
#pragma unroll
          for (int r = 0; r < 4; ++r)
            acc[fm][fn][r] = __expf(acc[fm][fn][r] + bc[fn] - 8.0f);
#pragma unroll
      for (int fm = 0; fm < 4; ++fm) {  // per-token rowsum -> P2
        f32x4 rs;
#pragma unroll
        for (int r = 0; r < 4; ++r) {
          float t2 = (acc[fm][0][r] + acc[fm][1][r]) + (acc[fm][2][r] + acc[fm][3][r]);
#pragma unroll
          for (int m = 1; m < 16; m <<= 1) t2 += __shfl_xor(t2, m);
          rs[r] = t2;
        }
#pragma unroll
        for (int r = 0; r < 4; ++r) {
          float rinv = 1.f / rs[r];
          int n = bm + wm + fm * 16 + g * 4 + r;
#pragma unroll
          for (int fn = 0; fn < 4; ++fn)
            P2[(size_t)n * 512 + h * 64 + fn * 16 + l] = f2bf(acc[fm][fn][r] * rinv);
        }
      }
#pragma unroll
      for (int fm = 0; fm < 4; ++fm)  // E^T into LDS
#pragma unroll
        for (int fn = 0; fn < 4; ++fn)
#pragma unroll
          for (int r = 0; r < 4; ++r)
            ET[(fn * 16 + l) * 136 + wm + fm * 16 + g * 4 + r] = f2bf(acc[fm][fn][r]);
#pragma unroll
      for (int fn = 0; fn < 4; ++fn) {  // per-slot colsum partials
        float t2 = 0.f;
#pragma unroll
        for (int fm = 0; fm < 4; ++fm)
#pragma unroll
          for (int r = 0; r < 4; ++r) t2 += acc[fm][fn][r];
        t2 += __shfl_xor(t2, 16);
        t2 += __shfl_xor(t2, 32);
        if (g == 0) denp[(w >> 1) * 64 + fn * 16 + l] = t2;
      }
    } else {  // V-waves (cols 64..127 = dims)
#pragma unroll
      for (int fm = 0; fm < 4; ++fm)
#pragma unroll
        for (int fn = 0; fn < 4; ++fn)
#pragma unroll
          for (int r = 0; r < 4; ++r)
            VT[(fn * 16 + l) * 136 + wm + fm * 16 + g * 4 + r] =
                f2bf(acc[fm][fn][r] + bc[fn]);
    }
    __syncthreads();
    // z += E^T @ V over this tile's 128 tokens (all 4 waves, 16 s-rows each)
#pragma unroll
    for (int ks2 = 0; ks2 < 4; ++ks2) {
      bf16x8 a2 = *(const bf16x8*)&ET[(w * 16 + l) * 136 + ks2 * 32 + g * 8];
#pragma unroll
      for (int fd = 0; fd < 4; ++fd) {
        bf16x8 b2 = *(const bf16x8*)&VT[(fd * 16 + l) * 136 + ks2 * 32 + g * 8];
        za[fd] = mfma16(a2, b2, za[fd]);
      }
    }
    dtot += denp[lane] + denp[64 + lane];
    __syncthreads();  // ET/VT reads done before next tile's staging overwrites
  }

  if (MODE == 1) {
    size_t mh = (size_t)group * 8 + h;
#pragma unroll
    for (int fd = 0; fd < 4; ++fd)
#pragma unroll
      for (int r = 0; r < 4; ++r)
        zpart[mh * 4096 + (w * 16 + g * 4 + r) * 64 + fd * 16 + l] = za[fd][r];
    if (w == 0) dpart[mh * 64 + lane] = dtot;
  }
}

// ---------------- reduce partials -> z fp32 [bh][s][d] ----------------
__global__ void k_zred(const float* __restrict__ zpart, const float* __restrict__ dpart,
                       float* __restrict__ z) {
  int idx = blockIdx.x * 256 + threadIdx.x;  // 131072
  int bh = idx >> 12, s = (idx >> 6) & 63, d = idx & 63;
  int b = bh >> 3, h = bh & 7;
  float num = 0.f, den = 0.f;
  for (int c = 0; c < 32; ++c) {
    size_t mh = ((size_t)(b * 32 + c)) * 8 + h;
    num += zpart[mh * 4096 + s * 64 + d];
    den += dpart[mh * 64 + s];
  }
  z[idx] = num / den;
}

// ---------------- zWoT[b][c][hs] = sum_d z[b,h,s,d] * WoT[c][h*64+d] ----------------
__global__ void k_zwo(const float* __restrict__ z, const unsigned short* __restrict__ WoT,
                      unsigned short* __restrict__ zWoT) {
  int idx = blockIdx.x * 256 + threadIdx.x;  // 1048576
  int hs = idx & 511, c = (idx >> 9) & 511, b = idx >> 18;
  int h = hs >> 6;
  const float* zp = z + ((size_t)(b * 8 + h) * 64 + (hs & 63)) * 64;
  const unsigned short* wp = WoT + (size_t)c * 512 + h * 64;
  float a = 0.f;
#pragma unroll 8
  for (int d = 0; d < 64; ++d) a += zp[d] * bf2f(wp[d]);
  zWoT[((size_t)(b * 512) + c) * 512 + hs] = f2bf(a);
}

extern "C" void kernel_launch(void* const* d_in, const int* in_sizes, int n_in,
                              void* d_out, int out_size, void* d_ws, size_t ws_size,
                              hipStream_t stream) {
  const float* x  = (const float*)d_in[0];
  const float* qg = (const float*)d_in[1];
  const float* Wx = (const float*)d_in[2];
  const float* bx = (const float*)d_in[3];
  const float* Wk = (const float*)d_in[4];
  const float* bk = (const float*)d_in[5];
  const float* Wv = (const float*)d_in[6];
  const float* bv = (const float*)d_in[7];
  const float* Wo = (const float*)d_in[8];
  const float* bo = (const float*)d_in[9];
  float* out = (float*)d_out;

  char* ws = (char*)d_ws;
  unsigned short* xbf  = (unsigned short*)(ws);               // 64 MiB
  unsigned short* P2   = (unsigned short*)(ws + 67108864);    // 64 MiB
  unsigned short* Wcat = (unsigned short*)(ws + 134217728);   // 1 MiB
  unsigned short* WoT  = (unsigned short*)(ws + 135266304);   // 0.5 MiB
  float* bias          = (float*)(ws + 135790592);            // 4 KiB
  float* GK            = (float*)(ws + 135794688);            // 128 KiB
  unsigned short* zWoT = (unsigned short*)(ws + 135925760);   // 2 MiB
  float* zbuf          = (float*)(ws + 138027008);            // 512 KiB
  // d_out doubles as scratch (dead before GEMM2 writes it):
  char* dob = (char*)d_out;
  float* zpart = (float*)(dob);                               // 16 MiB
  float* dpart = (float*)(dob + 16777216);                    // 256 KiB

  k_misc1<<<dim3(16512), dim3(256), 0, stream>>>(x, xbf, Wk, qg, GK);
  k_misc2<<<dim3(3076), dim3(256), 0, stream>>>(Wx, Wv, Wo, bx, bk, bv, qg, GK,
                                                Wcat, WoT, bias);
  // GEMM1 + fused z: grid 1024 (4 mtiles x 1 head per block)
  k_mm<1><<<dim3(1024), dim3(256), 0, stream>>>(xbf, Wcat, bias, P2, zpart, dpart, nullptr);
  k_zred<<<dim3(512), dim3(256), 0, stream>>>(zpart, dpart, zbuf);
  k_zwo<<<dim3(4096), dim3(256), 0, stream>>>(zbuf, WoT, zWoT);
  // GEMM2: out = P2 @ zWoT_b^T + bo (swapped-operand, dwordx4 stores)
  k_mm<0><<<dim3(2048), dim3(256), 0, stream>>>(P2, zWoT, bo, nullptr, nullptr, nullptr, out);
}

// Round 9
// 262.153 us; speedup vs baseline: 1.5352x; 1.5352x over previous
//
#include <hip/hip_runtime.h>
#include <stdint.h>

#define DEV __device__ __forceinline__

typedef __attribute__((ext_vector_type(8))) short bf16x8;
typedef __attribute__((ext_vector_type(4))) float f32x4;
typedef __attribute__((ext_vector_type(8))) unsigned short u16x8;

DEV unsigned short f2bf(float f) {
  union { float f; unsigned int u; } v; v.f = f;
  unsigned int u = v.u;
  return (unsigned short)((u + 0x7FFFu + ((u >> 16) & 1u)) >> 16);
}
DEV float bf2f(unsigned short u) {
  union { unsigned int u; float f; } v; v.u = ((unsigned int)u) << 16;
  return v.f;
}
DEV f32x4 mfma16(bf16x8 a, bf16x8 b, f32x4 c) {
  return __builtin_amdgcn_mfma_f32_16x16x32_bf16(a, b, c, 0, 0, 0);
}
DEV void gl_lds16(const void* g, void* l) {
  __builtin_amdgcn_global_load_lds(
      (const __attribute__((address_space(1))) void*)g,
      (__attribute__((address_space(3))) void*)l, 16, 0, 0);
}

// ======== launch 1: cvt (blocks 0..16383) + GK (blocks 16384..16511) ========
__global__ __launch_bounds__(256) void k_misc1(const float* __restrict__ x,
                                               unsigned short* __restrict__ xbf,
                                               const float* __restrict__ Wk,
                                               const float* __restrict__ qg,
                                               float* __restrict__ GK) {
  int bid = blockIdx.x;
  if (bid < 16384) {
    int i = bid * 256 + threadIdx.x;
    const float4* p = (const float4*)x + (size_t)i * 2;
    float4 a = p[0], b = p[1];
    u16x8 o;
    o[0] = f2bf(a.x); o[1] = f2bf(a.y); o[2] = f2bf(a.z); o[3] = f2bf(a.w);
    o[4] = f2bf(b.x); o[5] = f2bf(b.y); o[6] = f2bf(b.z); o[7] = f2bf(b.w);
    ((u16x8*)xbf)[i] = o;
  } else {
    int idx = (bid - 16384) * 256 + threadIdx.x;  // 32768: GK[h][s][dd]
    int dd = idx & 63, hs = idx >> 6;
    float a = 0.f;
#pragma unroll 8
    for (int d = 0; d < 64; ++d) a += Wk[dd * 64 + d] * qg[(size_t)hs * 64 + d];
    GK[idx] = a;
  }
}

// ======== launch 2: Wcat (head-interleaved) + WoT + bias ========
__global__ __launch_bounds__(256) void k_misc2(const float* __restrict__ Wx,
                                               const float* __restrict__ Wv,
                                               const float* __restrict__ Wo,
                                               const float* __restrict__ bx,
                                               const float* __restrict__ bk,
                                               const float* __restrict__ bv,
                                               const float* __restrict__ qg,
                                               const float* __restrict__ GK,
                                               unsigned short* __restrict__ Wcat,
                                               unsigned short* __restrict__ WoT,
                                               float* __restrict__ bias) {
  int bid = blockIdx.x;
  if (bid < 1024) {  // Wl^T rows h*128+s
    int idx = bid * 256 + threadIdx.x;
    int c = idx & 511, hs = idx >> 9;
    int h = hs >> 6, s = hs & 63;
    float a = 0.f;
#pragma unroll 8
    for (int dd = 0; dd < 64; ++dd) a += Wx[(size_t)c * 512 + h * 64 + dd] * GK[hs * 64 + dd];
    Wcat[(size_t)(h * 128 + s) * 512 + c] = f2bf(a);
  } else if (bid < 2048) {  // Wv^T fused rows h*128+64+dp
    int idx = (bid - 1024) * 256 + threadIdx.x;
    int c = idx & 511, o = idx >> 9;
    int h = o >> 6, dp = o & 63;
    float a = 0.f;
#pragma unroll 8
    for (int dd = 0; dd < 64; ++dd) a += Wx[(size_t)c * 512 + h * 64 + dd] * Wv[dd * 64 + dp];
    Wcat[(size_t)(h * 128 + 64 + dp) * 512 + c] = f2bf(a);
  } else if (bid < 3072) {  // WoT
    int idx = (bid - 2048) * 256 + threadIdx.x;
    int i = idx >> 9, o = idx & 511;
    WoT[(size_t)o * 512 + i] = f2bf(Wo[(size_t)i * 512 + o]);
  } else {  // bias head-interleaved: o=h*128+j; j<64 -> L-bias(h,s=j); else V-bias
    int o = (bid - 3072) * 256 + threadIdx.x;
    if (o >= 1024) return;
    int h = o >> 7, j = o & 127;
    if (j < 64) {
      int hs = h * 64 + j;
      float a = 0.f;
      for (int dd = 0; dd < 64; ++dd) a += bx[h * 64 + dd] * GK[(size_t)hs * 64 + dd];
      for (int dp = 0; dp < 64; ++dp) a += bk[dp] * qg[(size_t)hs * 64 + dp];
      bias[o] = a;
    } else {
      int dp = j - 64;
      float a = bv[dp];
      for (int dd = 0; dd < 64; ++dd) a += bx[h * 64 + dd] * Wv[dd * 64 + dp];
      bias[o] = a;
    }
  }
}

// =================== 128x128 GEMM, 4 waves, swizzled LDS, 4 blocks/CU ===================
// R7-proven structure (93 us, MfmaUtil 34%): per K-tile {gl_lds stage -> sync ->
// 32 MFMA -> sync}; cross-block overlap (4 blocks/CU, staggered grids) hides drains.
// MODE 1 (GEMM1, ntile=head): E-cols exp/rowsum/P2 + z=E^T@V via LDS transpose.
// MODE 0 (GEMM2): out = P2 @ zWoT_b^T + bo, column-coalesced scalar stores.
template <int MODE>
__global__ __launch_bounds__(256, 4) void k_mm(const unsigned short* __restrict__ A,
                                               const unsigned short* __restrict__ BTg,
                                               const float* __restrict__ bias,
                                               unsigned short* __restrict__ P2,
                                               float* __restrict__ zpart,
                                               float* __restrict__ dpart,
                                               float* __restrict__ outF) {
  __shared__ __align__(16) char lds[35328];
  const int tid = threadIdx.x;
  const int w = tid >> 6, lane = tid & 63, l = lane & 15, g = lane >> 4;
  unsigned bid = blockIdx.x;
  int mtile, ntile;
  if (MODE == 1) {  // 4096 blocks: XCD-chunked, 8 heads of one mtile adjacent
    unsigned nbid = (bid & 7) * 512 + (bid >> 3);
    mtile = nbid >> 3;
    ntile = nbid & 7;
  } else {  // 2048 blocks
    unsigned nbid = (bid & 7) * 256 + (bid >> 3);
    mtile = nbid >> 2;
    ntile = nbid & 3;
  }
  const int bm = mtile * 128;
  const int bn = ntile * 128;
  const int b = mtile >> 7;
  const unsigned short* BT = (MODE == 0) ? BTg + ((size_t)b << 18) : BTg;
  const int wm = (w >> 1) * 64, wn = (w & 1) * 64;
  char* As = lds;
  char* Bs = lds + 16384;
  f32x4 acc[4][4] = {};
  const int sw = (l & 7) << 4;

  for (int t = 0; t < 8; ++t) {
#pragma unroll
    for (int i = 0; i < 4; ++i) {  // stage 16KB each of A,B (pre-swizzled src)
      int off = i * 4096 + tid * 16;
      int row = off >> 7;
      int cb = (off & 127) ^ ((row & 7) << 4);
      gl_lds16(A + (size_t)(bm + row) * 512 + t * 64 + (cb >> 1), As + off);
      gl_lds16(BT + (size_t)(bn + row) * 512 + t * 64 + (cb >> 1), Bs + off);
    }
    __syncthreads();
#pragma unroll
    for (int ks = 0; ks < 2; ++ks) {
      int kb = (ks * 64 + g * 16) ^ sw;
      bf16x8 af[4], bf[4];
#pragma unroll
      for (int fm = 0; fm < 4; ++fm)
        af[fm] = *(const bf16x8*)(As + (wm + fm * 16 + l) * 128 + kb);
#pragma unroll
      for (int fn = 0; fn < 4; ++fn)
        bf[fn] = *(const bf16x8*)(Bs + (wn + fn * 16 + l) * 128 + kb);
#pragma unroll
      for (int fm = 0; fm < 4; ++fm)
#pragma unroll
        for (int fn = 0; fn < 4; ++fn)
          acc[fm][fn] = mfma16(af[fm], bf[fn], acc[fm][fn]);
    }
    __syncthreads();
  }

  if (MODE == 0) {
#pragma unroll
    for (int fm = 0; fm < 4; ++fm)
#pragma unroll
      for (int fn = 0; fn < 4; ++fn) {
        int col = bn + wn + fn * 16 + l;
        float bb = bias[col];
#pragma unroll
        for (int r = 0; r < 4; ++r)
          outF[(size_t)(bm + wm + fm * 16 + g * 4 + r) * 512 + col] = acc[fm][fn][r] + bb;
      }
    return;
  }

  // ================= MODE 1 epilogue (LDS staging dead) =================
  const int h = ntile;
  unsigned short* ET = (unsigned short*)lds;            // [64 s][136]
  unsigned short* VT = (unsigned short*)(lds + 17408);  // [64 d][136]
  float* denp = (float*)(lds + 34816);                  // [2][64]
  float bc[4];
#pragma unroll
  for (int fn = 0; fn < 4; ++fn) bc[fn] = bias[h * 128 + wn + fn * 16 + l];
  if (wn == 0) {  // E-waves (cols 0..63 = slots)
#pragma unroll
    for (int fm = 0; fm < 4; ++fm)
#pragma unroll
      for (int fn = 0; fn < 4; ++fn)
#pragma unroll
        for (int r = 0; r < 4; ++r)
          acc[fm][fn][r] = __expf(acc[fm][fn][r] + bc[fn] - 8.0f);
#pragma unroll
    for (int fm = 0; fm < 4; ++fm) {  // per-token rowsum -> P2
      f32x4 rs;
#pragma unroll
      for (int r = 0; r < 4; ++r) {
        float t2 = (acc[fm][0][r] + acc[fm][1][r]) + (acc[fm][2][r] + acc[fm][3][r]);
#pragma unroll
        for (int m = 1; m < 16; m <<= 1) t2 += __shfl_xor(t2, m);
        rs[r] = t2;
      }
#pragma unroll
      for (int r = 0; r < 4; ++r) {
        float rinv = 1.f / rs[r];
        int n = bm + wm + fm * 16 + g * 4 + r;
#pragma unroll
        for (int fn = 0; fn < 4; ++fn)
          P2[(size_t)n * 512 + h * 64 + fn * 16 + l] = f2bf(acc[fm][fn][r] * rinv);
      }
    }
#pragma unroll
    for (int fm = 0; fm < 4; ++fm)  // E^T into LDS
#pragma unroll
      for (int fn = 0; fn < 4; ++fn)
#pragma unroll
        for (int r = 0; r < 4; ++r)
          ET[(fn * 16 + l) * 136 + wm + fm * 16 + g * 4 + r] = f2bf(acc[fm][fn][r]);
#pragma unroll
    for (int fn = 0; fn < 4; ++fn) {  // per-slot colsum partials
      float t2 = 0.f;
#pragma unroll
      for (int fm = 0; fm < 4; ++fm)
#pragma unroll
        for (int r = 0; r < 4; ++r) t2 += acc[fm][fn][r];
      t2 += __shfl_xor(t2, 16);
      t2 += __shfl_xor(t2, 32);
      if (g == 0) denp[(w >> 1) * 64 + fn * 16 + l] = t2;
    }
  } else {  // V-waves (cols 64..127 = dims)
#pragma unroll
    for (int fm = 0; fm < 4; ++fm)
#pragma unroll
      for (int fn = 0; fn < 4; ++fn)
#pragma unroll
        for (int r = 0; r < 4; ++r)
          VT[(fn * 16 + l) * 136 + wm + fm * 16 + g * 4 + r] =
              f2bf(acc[fm][fn][r] + bc[fn]);
  }
  __syncthreads();
  // z_part[s][d] = E^T @ V over this tile's 128 tokens (4 waves, 16 s-rows each)
  f32x4 za[4] = {};
#pragma unroll
  for (int ks2 = 0; ks2 < 4; ++ks2) {
    bf16x8 a2 = *(const bf16x8*)&ET[(w * 16 + l) * 136 + ks2 * 32 + g * 8];
#pragma unroll
    for (int fd = 0; fd < 4; ++fd) {
      bf16x8 b2 = *(const bf16x8*)&VT[(fd * 16 + l) * 136 + ks2 * 32 + g * 8];
      za[fd] = mfma16(a2, b2, za[fd]);
    }
  }
  size_t mh = (size_t)mtile * 8 + h;
#pragma unroll
  for (int fd = 0; fd < 4; ++fd)
#pragma unroll
    for (int r = 0; r < 4; ++r)
      zpart[mh * 4096 + (w * 16 + g * 4 + r) * 64 + fd * 16 + l] = za[fd][r];
  if (w == 0) dpart[mh * 64 + lane] = denp[lane] + denp[64 + lane];
}

// ---------------- reduce partials -> z fp32 [bh][s][d] ----------------
__global__ void k_zred(const float* __restrict__ zpart, const float* __restrict__ dpart,
                       float* __restrict__ z) {
  int idx = blockIdx.x * 256 + threadIdx.x;  // 131072
  int bh = idx >> 12, s = (idx >> 6) & 63, d = idx & 63;
  int b = bh >> 3, h = bh & 7;
  float num = 0.f, den = 0.f;
  for (int mm = 0; mm < 128; ++mm) {
    size_t mh = ((size_t)(b * 128 + mm)) * 8 + h;
    num += zpart[mh * 4096 + s * 64 + d];
    den += dpart[mh * 64 + s];
  }
  z[idx] = num / den;
}

// ---------------- zWoT[b][c][hs] = sum_d z[b,h,s,d] * WoT[c][h*64+d] ----------------
__global__ void k_zwo(const float* __restrict__ z, const unsigned short* __restrict__ WoT,
                      unsigned short* __restrict__ zWoT) {
  int idx = blockIdx.x * 256 + threadIdx.x;  // 1048576
  int hs = idx & 511, c = (idx >> 9) & 511, b = idx >> 18;
  int h = hs >> 6;
  const float* zp = z + ((size_t)(b * 8 + h) * 64 + (hs & 63)) * 64;
  const unsigned short* wp = WoT + (size_t)c * 512 + h * 64;
  float a = 0.f;
#pragma unroll 8
  for (int d = 0; d < 64; ++d) a += zp[d] * bf2f(wp[d]);
  zWoT[((size_t)(b * 512) + c) * 512 + hs] = f2bf(a);
}

extern "C" void kernel_launch(void* const* d_in, const int* in_sizes, int n_in,
                              void* d_out, int out_size, void* d_ws, size_t ws_size,
                              hipStream_t stream) {
  const float* x  = (const float*)d_in[0];
  const float* qg = (const float*)d_in[1];
  const float* Wx = (const float*)d_in[2];
  const float* bx = (const float*)d_in[3];
  const float* Wk = (const float*)d_in[4];
  const float* bk = (const float*)d_in[5];
  const float* Wv = (const float*)d_in[6];
  const float* bv = (const float*)d_in[7];
  const float* Wo = (const float*)d_in[8];
  const float* bo = (const float*)d_in[9];
  float* out = (float*)d_out;

  char* ws = (char*)d_ws;
  unsigned short* xbf  = (unsigned short*)(ws);               // 64 MiB
  unsigned short* P2   = (unsigned short*)(ws + 67108864);    // 64 MiB
  unsigned short* Wcat = (unsigned short*)(ws + 134217728);   // 1 MiB
  unsigned short* WoT  = (unsigned short*)(ws + 135266304);   // 0.5 MiB
  float* bias          = (float*)(ws + 135790592);            // 4 KiB
  float* GK            = (float*)(ws + 135794688);            // 128 KiB
  unsigned short* zWoT = (unsigned short*)(ws + 135925760);   // 2 MiB
  float* zbuf          = (float*)(ws + 138027008);            // 512 KiB
  // d_out doubles as scratch (dead before GEMM2 writes it):
  char* dob = (char*)d_out;
  float* zpart = (float*)(dob);                               // 64 MiB
  float* dpart = (float*)(dob + 67108864);                    // 1 MiB

  k_misc1<<<dim3(16512), dim3(256), 0, stream>>>(x, xbf, Wk, qg, GK);
  k_misc2<<<dim3(3076), dim3(256), 0, stream>>>(Wx, Wv, Wo, bx, bk, bv, qg, GK,
                                                Wcat, WoT, bias);
  // GEMM1 + fused z: per (mtile, head) -> P2, zpart, dpart
  k_mm<1><<<dim3(4096), dim3(256), 0, stream>>>(xbf, Wcat, bias, P2, zpart, dpart, nullptr);
  k_zred<<<dim3(512), dim3(256), 0, stream>>>(zpart, dpart, zbuf);
  k_zwo<<<dim3(4096), dim3(256), 0, stream>>>(zbuf, WoT, zWoT);
  // GEMM2: out = P2 @ zWoT_b^T + bo
  k_mm<0><<<dim3(2048), dim3(256), 0, stream>>>(P2, zWoT, bo, nullptr, nullptr, nullptr, out);
}